// Round 1
// baseline (165.019 us; speedup 1.0000x reference)
//
#include <hip/hip_runtime.h>
#include <math.h>

// Problem dims (fixed by reference)
#define SE_B 64
#define SE_C 256
#define SE_L 4096
#define SE_R 16

// ---------------------------------------------------------------------------
// Kernel 1: per-(b,c) mean over L. One block per row, 256 threads.
// Each thread loads 4 float4 (16 floats) -> 4096 / row. Wave+LDS reduce.
// ---------------------------------------------------------------------------
__global__ __launch_bounds__(256) void se_mean_kernel(
    const float* __restrict__ x, float* __restrict__ means) {
  const int row = blockIdx.x;  // b*C + c
  const int t = threadIdx.x;
  const float4* __restrict__ xrow =
      reinterpret_cast<const float4*>(x + (size_t)row * SE_L);
  float s = 0.0f;
#pragma unroll
  for (int i = 0; i < 4; ++i) {
    float4 v = xrow[t + i * 256];  // coalesced: consecutive lanes -> consecutive 16B
    s += (v.x + v.y) + (v.z + v.w);
  }
  // 64-lane wave butterfly reduce
#pragma unroll
  for (int off = 32; off > 0; off >>= 1) s += __shfl_down(s, off, 64);
  __shared__ float partial[4];
  if ((t & 63) == 0) partial[t >> 6] = s;
  __syncthreads();
  if (t == 0) {
    float tot = (partial[0] + partial[1]) + (partial[2] + partial[3]);
    means[row] = tot * (1.0f / SE_L);
  }
}

// ---------------------------------------------------------------------------
// Kernel 2: tiny 2-layer MLP gate per batch. One block per b, 256 threads.
// y[r]   = relu(sum_c mean[b,c] * w1[r,c] + b1[r])       (w1 is [R,C])
// g[c]   = sigmoid(sum_r y[r] * w2[c,r] + b2[c])         (w2 is [C,R])
// ---------------------------------------------------------------------------
__global__ __launch_bounds__(256) void se_gate_kernel(
    const float* __restrict__ means, const float* __restrict__ w1,
    const float* __restrict__ b1, const float* __restrict__ w2,
    const float* __restrict__ b2, float* __restrict__ gates) {
  const int b = blockIdx.x;
  const int t = threadIdx.x;
  __shared__ float m[SE_C];
  __shared__ float y[SE_R];
  m[t] = means[b * SE_C + t];
  __syncthreads();
  if (t < SE_R) {
    float acc = b1[t];
    const float* __restrict__ w1r = w1 + t * SE_C;
#pragma unroll 8
    for (int c = 0; c < SE_C; ++c) acc += m[c] * w1r[c];
    y[t] = fmaxf(acc, 0.0f);
  }
  __syncthreads();
  float g = b2[t];
  const float* __restrict__ w2r = w2 + t * SE_R;
#pragma unroll
  for (int r = 0; r < SE_R; ++r) g += y[r] * w2r[r];
  gates[b * SE_C + t] = 1.0f / (1.0f + expf(-g));
}

// ---------------------------------------------------------------------------
// Kernel 3: out[b,c,l] = x[b,c,l] * gate[b,c]. Grid-stride float4.
// Row of a float4 index i is i >> 10 (L/4 = 1024 float4 per row).
// ---------------------------------------------------------------------------
__global__ __launch_bounds__(256) void se_scale_kernel(
    const float* __restrict__ x, const float* __restrict__ gates,
    float* __restrict__ out) {
  const size_t n4 = (size_t)SE_B * SE_C * (SE_L / 4);  // 16,777,216
  const size_t stride = (size_t)gridDim.x * blockDim.x;
  const float4* __restrict__ x4 = reinterpret_cast<const float4*>(x);
  float4* __restrict__ o4 = reinterpret_cast<float4*>(out);
  for (size_t i = (size_t)blockIdx.x * blockDim.x + threadIdx.x; i < n4;
       i += stride) {
    const int row = (int)(i >> 10);
    const float g = gates[row];
    float4 v = x4[i];
    v.x *= g;
    v.y *= g;
    v.z *= g;
    v.w *= g;
    o4[i] = v;
  }
}

extern "C" void kernel_launch(void* const* d_in, const int* in_sizes, int n_in,
                              void* d_out, int out_size, void* d_ws,
                              size_t ws_size, hipStream_t stream) {
  const float* x = (const float*)d_in[0];
  const float* w1 = (const float*)d_in[1];
  const float* b1 = (const float*)d_in[2];
  const float* w2 = (const float*)d_in[3];
  const float* b2 = (const float*)d_in[4];
  float* out = (float*)d_out;

  float* means = (float*)d_ws;             // B*C floats
  float* gates = means + SE_B * SE_C;      // B*C floats

  se_mean_kernel<<<SE_B * SE_C, 256, 0, stream>>>(x, means);
  se_gate_kernel<<<SE_B, SE_C, 0, stream>>>(means, w1, b1, w2, b2, gates);
  // 2048 blocks x 256 threads, grid-stride (32 float4 per thread)
  se_scale_kernel<<<2048, 256, 0, stream>>>(x, gates, out);
}

// Round 3
// 131.617 us; speedup vs baseline: 1.2538x; 1.2538x over previous
//
#include <hip/hip_runtime.h>
#include <math.h>

// Problem dims (fixed by reference)
#define SE_B 64
#define SE_C 256
#define SE_L 4096
#define SE_R 16

// Clang native vector type — required by __builtin_nontemporal_store
// (HIP's float4 is a struct and is rejected).
typedef float vf4 __attribute__((ext_vector_type(4)));

// ---------------------------------------------------------------------------
// Kernel 1: per-(b,c) mean over L. One block per row, 256 threads.
// Each thread loads 4 float4 (16 floats) -> 4096 / row. Wave+LDS reduce.
// ---------------------------------------------------------------------------
__global__ __launch_bounds__(256) void se_mean_kernel(
    const float* __restrict__ x, float* __restrict__ means) {
  const int row = blockIdx.x;  // b*C + c
  const int t = threadIdx.x;
  const vf4* __restrict__ xrow =
      reinterpret_cast<const vf4*>(x + (size_t)row * SE_L);
  float s = 0.0f;
#pragma unroll
  for (int i = 0; i < 4; ++i) {
    vf4 v = xrow[t + i * 256];  // coalesced: consecutive lanes -> consecutive 16B
    s += (v.x + v.y) + (v.z + v.w);
  }
  // 64-lane wave butterfly reduce
#pragma unroll
  for (int off = 32; off > 0; off >>= 1) s += __shfl_down(s, off, 64);
  __shared__ float partial[4];
  if ((t & 63) == 0) partial[t >> 6] = s;
  __syncthreads();
  if (t == 0) {
    float tot = (partial[0] + partial[1]) + (partial[2] + partial[3]);
    means[row] = tot * (1.0f / SE_L);
  }
}

// ---------------------------------------------------------------------------
// Kernel 2: tiny 2-layer MLP gate per batch. One block per b, 256 threads.
// y[r]   = relu(sum_c mean[b,c] * w1[r,c] + b1[r])       (w1 is [R,C])
// g[c]   = sigmoid(sum_r y[r] * w2[c,r] + b2[c])         (w2 is [C,R])
// ---------------------------------------------------------------------------
__global__ __launch_bounds__(256) void se_gate_kernel(
    const float* __restrict__ means, const float* __restrict__ w1,
    const float* __restrict__ b1, const float* __restrict__ w2,
    const float* __restrict__ b2, float* __restrict__ gates) {
  const int b = blockIdx.x;
  const int t = threadIdx.x;
  __shared__ float m[SE_C];
  __shared__ float y[SE_R];
  m[t] = means[b * SE_C + t];
  __syncthreads();
  if (t < SE_R) {
    float acc = b1[t];
    const float* __restrict__ w1r = w1 + t * SE_C;
#pragma unroll 8
    for (int c = 0; c < SE_C; ++c) acc += m[c] * w1r[c];
    y[t] = fmaxf(acc, 0.0f);
  }
  __syncthreads();
  float g = b2[t];
  const float* __restrict__ w2r = w2 + t * SE_R;
#pragma unroll
  for (int r = 0; r < SE_R; ++r) g += y[r] * w2r[r];
  gates[b * SE_C + t] = 1.0f / (1.0f + expf(-g));
}

// ---------------------------------------------------------------------------
// Kernel 3: out[b,c,l] = x[b,c,l] * gate[b,c]. Grid-stride vf4.
// Row of a float4 index i is i >> 10 (L/4 = 1024 float4 per row).
// Store is NON-TEMPORAL: out (256 MB/iter) must not allocate in L3, so x
// (256 MB == L3 size) stays Infinity-Cache-resident across graph replays.
// ---------------------------------------------------------------------------
__global__ __launch_bounds__(256) void se_scale_kernel(
    const float* __restrict__ x, const float* __restrict__ gates,
    float* __restrict__ out) {
  const size_t n4 = (size_t)SE_B * SE_C * (SE_L / 4);  // 16,777,216
  const size_t stride = (size_t)gridDim.x * blockDim.x;
  const vf4* __restrict__ x4 = reinterpret_cast<const vf4*>(x);
  vf4* __restrict__ o4 = reinterpret_cast<vf4*>(out);
  for (size_t i = (size_t)blockIdx.x * blockDim.x + threadIdx.x; i < n4;
       i += stride) {
    const int row = (int)(i >> 10);
    const float g = gates[row];
    vf4 v = x4[i];
    v *= g;
    __builtin_nontemporal_store(v, &o4[i]);
  }
}

extern "C" void kernel_launch(void* const* d_in, const int* in_sizes, int n_in,
                              void* d_out, int out_size, void* d_ws,
                              size_t ws_size, hipStream_t stream) {
  const float* x = (const float*)d_in[0];
  const float* w1 = (const float*)d_in[1];
  const float* b1 = (const float*)d_in[2];
  const float* w2 = (const float*)d_in[3];
  const float* b2 = (const float*)d_in[4];
  float* out = (float*)d_out;

  float* means = (float*)d_ws;             // B*C floats
  float* gates = means + SE_B * SE_C;      // B*C floats

  se_mean_kernel<<<SE_B * SE_C, 256, 0, stream>>>(x, means);
  se_gate_kernel<<<SE_B, SE_C, 0, stream>>>(means, w1, b1, w2, b2, gates);
  // 2048 blocks x 256 threads, grid-stride (32 float4 per thread)
  se_scale_kernel<<<2048, 256, 0, stream>>>(x, gates, out);
}